// Round 7
// baseline (311.522 us; speedup 1.0000x reference)
//
#include <hip/hip_runtime.h>
#include <hip/hip_bf16.h>

typedef unsigned short u16;
typedef unsigned int u32;
typedef __attribute__((ext_vector_type(8))) short short8x;   // 8 bf16 (4 VGPR)
typedef __attribute__((ext_vector_type(4))) float f32x4;

__device__ __forceinline__ u16 bf16u(float x) {
    __hip_bfloat16 h = __float2bfloat16(x);
    return *reinterpret_cast<u16*>(&h);
}

__device__ __forceinline__ void gload_lds16(const void* g, void* l) {
    __builtin_amdgcn_global_load_lds(
        (const __attribute__((address_space(1))) u32*)g,
        (__attribute__((address_space(3))) u32*)l, 16, 0, 0);
}

// m=64, n=1024, W=H=512
#define M_  64
#define N_  1024
#define W_  512
#define SP_ROW 163840   // packed S' row length per i: 10 tiles * 16384

// ---------------------------------------------------------------------------
// K1: normalize psi rows (axis=2) and write transposed bf16 psiT[i][w][n].
// 4 passes x 16 rows: <=~50 live VGPR (no spill), norm via 16-lane shfl_xor
// (no LDS/barrier), loads are 4x256B contiguous chunks per wave-inst.
// Transposed store: u32 n-pairs, 256B per wave-inst.
// grid (16, 64): 64 n-rows of one i per block. block=256.
// ---------------------------------------------------------------------------
__global__ __launch_bounds__(256) void psinorm_t(const float* __restrict__ psi,
                                                 u16* __restrict__ psiT) {
    const int i  = blockIdx.y;
    const int nb = blockIdx.x;          // 64-row chunk
    const int t  = threadIdx.x;
    const float* base = psi + ((size_t)i * N_ + (size_t)nb * 64) * W_;

    __shared__ u32 tile[64][257];       // u16[64][514]; row pitch 257 u32

    const int sub = t & 15;             // 16 threads per row

#pragma unroll
    for (int pp = 0; pp < 4; ++pp) {
        const int r = pp * 16 + (t >> 4);
        const float4* rb = (const float4*)(base + (size_t)r * W_) + sub;
        float4 v[8];
        float s = 0.f;
#pragma unroll
        for (int k = 0; k < 8; ++k) {
            v[k] = rb[k * 16];          // bytes: r*2048 + sub*16 + k*256
            s += v[k].x * v[k].x + v[k].y * v[k].y + v[k].z * v[k].z + v[k].w * v[k].w;
        }
        // reduce across the 16 lanes sharing this row (butterfly -> all lanes)
#pragma unroll
        for (int o = 1; o < 16; o <<= 1) s += __shfl_xor(s, o);
        const float inv = 1.0f / fmaxf(sqrtf(s), 1e-12f);
#pragma unroll
        for (int k = 0; k < 8; ++k) {
            u32 p0 = (u32)bf16u(v[k].x * inv) | ((u32)bf16u(v[k].y * inv) << 16);
            u32 p1 = (u32)bf16u(v[k].z * inv) | ((u32)bf16u(v[k].w * inv) << 16);
            const int wh = sub * 2 + k * 32;    // u32 col; w = sub*4 + k*64
            tile[r][wh]     = p0;               // banks 2-way aliased: free
            tile[r][wh + 1] = p1;
        }
    }
    __syncthreads();

    // transposed write: psiT[i][w][nb*64 + nn], u32 packs (nn=2q, 2q+1).
    // Per iter: wave covers 2 w-rows x 32 n-pairs (two 128B segments).
    {
        const u16* t16 = (const u16*)&tile[0][0];
        const int lane = t & 63, wv = t >> 6;
        const int q  = lane & 31;               // n-pair index
        const int l5 = lane >> 5;               // which of the 2 w's
        u32* out32 = (u32*)psiT + (size_t)i * (W_ * N_ / 2) + nb * 32;
#pragma unroll 4
        for (int it = 0; it < 64; ++it) {
            const int w = it * 8 + wv * 2 + l5;
            u32 lo = (u32)t16[(2 * q)     * 514 + w];   // 2-way bank alias: free
            u32 hi = (u32)t16[(2 * q + 1) * 514 + w];
            out32[(size_t)w * 512 + q] = lo | (hi << 16);
        }
    }
}

// ---------------------------------------------------------------------------
// K2: batched SYRK  S_i = psiT_i * psiT_i^T, upper-triangle 128x128 tiles only.
// psiT_i is 512(w) x 1024(n) bf16, k(=n)-contiguous: serves BOTH operands.
// grid 640 flat, XCD-swizzled: x=L&7, q=L>>3, i=x*8+q/10, bt=q%10 (bijective).
// block = 256 (4 waves, 2x2), BK = 64, 16 K-iters.
// T3-min double-buffer: STAGE(next) issued BEFORE compute(cur); one raw
// s_barrier + vmcnt(0) per iter AFTER compute -> staging latency hidden.
// XOR-swizzled LDS (source-side pre-swizzle, m173; involution on read).
// Output packed: Sp[i][tile] scaled by sqrt(2) on off-diag tiles so that
// b[i][j] = <Sp_i, Sp_j> reproduces the full Frobenius product exactly.
// ---------------------------------------------------------------------------
__global__ __launch_bounds__(256) void syrk_bf16(const u16* __restrict__ psiT,
                                                 u16* __restrict__ Sp) {
    const int L = blockIdx.x;
    const int q = L >> 3;
    const int i  = (L & 7) * 8 + q / 10;
    const int bt = q % 10;
    int tr, tc;
    if      (bt < 4) { tr = 0; tc = bt;     }
    else if (bt < 7) { tr = 1; tc = bt - 3; }
    else if (bt < 9) { tr = 2; tc = bt - 5; }
    else             { tr = 3; tc = 3;      }
    const int t = threadIdx.x;

    const u16* Abase = psiT + (size_t)i * W_ * N_ + (size_t)tr * 128 * N_;
    const u16* Bbase = psiT + (size_t)i * W_ * N_ + (size_t)tc * 128 * N_;

    __shared__ alignas(16) u16 ldsA[2][128][64];   // 2 x 16 KB
    __shared__ alignas(16) u16 ldsB[2][128][64];

    const int lane = t & 63, wv = t >> 6;
    const int wr = wv >> 1, wc = wv & 1;
    const int lrow = lane & 15, lk8 = lane >> 4;   // frag row / k-chunk

    // stage one K-tile (both operands) into buffer `buf`
    auto STAGE = [&](int buf, int kt) {
        const int k0 = kt * 64;
#pragma unroll
        for (int r = 0; r < 4; ++r) {
            int c = r * 256 + t;
            int row = c >> 3, cch = c & 7;
            int scch = cch ^ (row & 7);            // pre-swizzled source chunk
            gload_lds16(Abase + (size_t)row * N_ + k0 + scch * 8, &ldsA[buf][row][cch * 8]);
            gload_lds16(Bbase + (size_t)row * N_ + k0 + scch * 8, &ldsB[buf][row][cch * 8]);
        }
    };

    f32x4 acc[4][4];
#pragma unroll
    for (int a = 0; a < 4; ++a)
#pragma unroll
        for (int b = 0; b < 4; ++b) acc[a][b] = (f32x4){0.f, 0.f, 0.f, 0.f};

    STAGE(0, 0);
    asm volatile("s_waitcnt vmcnt(0)" ::: "memory");
    __builtin_amdgcn_s_barrier();

    int cur = 0;
    for (int kt = 0; kt < 16; ++kt) {
        if (kt < 15) STAGE(cur ^ 1, kt + 1);       // issue next-tile loads early
#pragma unroll
        for (int ks = 0; ks < 2; ++ks) {
            short8x af[4], bf[4];
#pragma unroll
            for (int mf = 0; mf < 4; ++mf) {
                int row = wr * 64 + mf * 16 + lrow;
                int ch = (ks * 4 + lk8) ^ (row & 7);
                af[mf] = *(const short8x*)&ldsA[cur][row][ch * 8];
            }
#pragma unroll
            for (int nf = 0; nf < 4; ++nf) {
                int row = wc * 64 + nf * 16 + lrow;
                int ch = (ks * 4 + lk8) ^ (row & 7);
                bf[nf] = *(const short8x*)&ldsB[cur][row][ch * 8];
            }
#pragma unroll
            for (int mf = 0; mf < 4; ++mf)
#pragma unroll
                for (int nf = 0; nf < 4; ++nf)
                    acc[mf][nf] = __builtin_amdgcn_mfma_f32_16x16x32_bf16(
                        af[mf], bf[nf], acc[mf][nf], 0, 0, 0);
        }
        // next-tile loads mostly landed during compute; drain remainder, sync
        asm volatile("s_waitcnt vmcnt(0)" ::: "memory");
        __builtin_amdgcn_sched_barrier(0);
        __builtin_amdgcn_s_barrier();
        cur ^= 1;
    }

    // epilogue: C/D layout col=lane&15, row=(lane>>4)*4+reg (m89-verified).
    const float sc = (tr == tc) ? 1.0f : 1.41421356237f;
    size_t Sbase = (size_t)i * SP_ROW + (size_t)bt * 16384;
#pragma unroll
    for (int mf = 0; mf < 4; ++mf)
#pragma unroll
        for (int nf = 0; nf < 4; ++nf)
#pragma unroll
            for (int reg = 0; reg < 4; ++reg) {
                int wl = wr * 64 + mf * 16 + lk8 * 4 + reg;
                int vl = wc * 64 + nf * 16 + lrow;
                Sp[Sbase + (size_t)wl * 128 + vl] = bf16u(acc[mf][nf][reg] * sc);
            }
}

// ---------------------------------------------------------------------------
// K3: b_partial = Sp * Sp^T over a 256-elem K-chunk (Sp: 64 x 163840 bf16).
// No LDS: per-block chunk is 32 KB, L1/L2-resident (4x reuse).
// grid 640, block 256 (4 waves 2x2, each 32x32 of the 64x64 output).
// ---------------------------------------------------------------------------
__global__ __launch_bounds__(256) void bgemm(const u16* __restrict__ Sp,
                                             float* __restrict__ bp) {
    const int t = threadIdx.x;
    const int lane = t & 63, wv = t >> 6;
    const int wr = wv >> 1, wc = wv & 1;
    const int lrow = lane & 15, lk8 = lane >> 4;
    const size_t kc0 = (size_t)blockIdx.x * 256;

    f32x4 acc[2][2];
#pragma unroll
    for (int a = 0; a < 2; ++a)
#pragma unroll
        for (int b = 0; b < 2; ++b) acc[a][b] = (f32x4){0.f, 0.f, 0.f, 0.f};

#pragma unroll
    for (int ks = 0; ks < 8; ++ks) {
        short8x af[2], bf[2];
#pragma unroll
        for (int mf = 0; mf < 2; ++mf) {
            int row = wr * 32 + mf * 16 + lrow;
            af[mf] = *(const short8x*)(Sp + (size_t)row * SP_ROW + kc0 + (ks * 4 + lk8) * 8);
        }
#pragma unroll
        for (int nf = 0; nf < 2; ++nf) {
            int row = wc * 32 + nf * 16 + lrow;
            bf[nf] = *(const short8x*)(Sp + (size_t)row * SP_ROW + kc0 + (ks * 4 + lk8) * 8);
        }
#pragma unroll
        for (int mf = 0; mf < 2; ++mf)
#pragma unroll
            for (int nf = 0; nf < 2; ++nf)
                acc[mf][nf] = __builtin_amdgcn_mfma_f32_16x16x32_bf16(
                    af[mf], bf[nf], acc[mf][nf], 0, 0, 0);
    }

    float* out = bp + (size_t)blockIdx.x * 4096;
#pragma unroll
    for (int mf = 0; mf < 2; ++mf)
#pragma unroll
        for (int nf = 0; nf < 2; ++nf)
#pragma unroll
            for (int reg = 0; reg < 4; ++reg) {
                int ir = wr * 32 + mf * 16 + lk8 * 4 + reg;
                int jc = wc * 32 + nf * 16 + lrow;
                out[ir * 64 + jc] = acc[mf][nf][reg];
            }
}

// ---------------------------------------------------------------------------
// K4: per block i: reduce b-row i over 640 partials; recompute phi norms/dots;
// parts[i] = sum_j (phi_i.phi_j)^2/(ni^2 nj^2) * b[i,j].  grid 64, block 256.
// ---------------------------------------------------------------------------
__global__ __launch_bounds__(256) void bfinal(const float* __restrict__ bp,
                                              const float* __restrict__ phi,
                                              float* __restrict__ parts) {
    const int i = blockIdx.x, t = threadIdx.x;
    const int lane = t & 63, wv = t >> 6;

    __shared__ float red[256];
    __shared__ float brow[64];
    __shared__ float pi[512];
    __shared__ float dj[64], nsq[64];

    // b-row reduction: 4 slices over partials
    {
        float s = 0.f;
        for (int p = wv; p < 640; p += 4) s += bp[(size_t)p * 4096 + i * 64 + lane];
        red[t] = s;
    }
    pi[t] = phi[i * 512 + t];
    pi[t + 256] = phi[i * 512 + 256 + t];
    __syncthreads();
    if (t < 64) brow[t] = red[t] + red[64 + t] + red[128 + t] + red[192 + t];

    // phi dots + norms (wave wv handles j = wv + 4*jj)
    for (int jj = 0; jj < 16; ++jj) {
        int j = wv + jj * 4;
        const float* pj = phi + j * 512;
        float d = 0.f, nn = 0.f;
#pragma unroll
        for (int e = 0; e < 8; ++e) {
            float x = pj[lane + e * 64];
            d += pi[lane + e * 64] * x;
            nn += x * x;
        }
#pragma unroll
        for (int o = 32; o; o >>= 1) {
            d += __shfl_xor(d, o);
            nn += __shfl_xor(nn, o);
        }
        if (lane == 0) { dj[j] = d; nsq[j] = nn; }
    }
    __syncthreads();
    if (t < 64) {
        float ni = fmaxf(sqrtf(nsq[i]), 1e-12f);
        float nj = fmaxf(sqrtf(nsq[t]), 1e-12f);
        float g = dj[t] / (ni * nj);
        float val = g * g * brow[t];
#pragma unroll
        for (int o = 32; o; o >>= 1) val += __shfl_down(val, o);
        if (t == 0) parts[i] = val;
    }
}

// K5: out = sum(parts) - m*n. grid 1, block 64.
__global__ void fsum(const float* __restrict__ parts, float* __restrict__ out) {
    const int t = threadIdx.x;
    float s = parts[t];
#pragma unroll
    for (int o = 32; o; o >>= 1) s += __shfl_down(s, o);
    if (t == 0) out[0] = s - 65536.0f;
}

// Fallback marker if workspace is too small (visible-wrong, not OOB-crash).
__global__ void wsfail(float* __restrict__ out) {
    if (threadIdx.x == 0) out[0] = 1.0e30f;
}

extern "C" void kernel_launch(void* const* d_in, const int* in_sizes, int n_in,
                              void* d_out, int out_size, void* d_ws, size_t ws_size,
                              hipStream_t stream) {
    const float* phi = (const float*)d_in[0];
    const float* psi = (const float*)d_in[1];
    float* out = (float*)d_out;
    char* ws = (char*)d_ws;

    // workspace layout (bytes), regions ALIASED by lifetime:
    //   [0 .. 64MB)      psiT  bf16 [64][512][1024]   (live: K1 -> K2)
    //   [0 .. 10.5MB)    bp    f32  [640][4096]       (live: K3 -> K4; aliases dead psiT)
    //   [64MB .. 84MB)   Sp    bf16 [64][163840]      (live: K2 -> K3)
    //   [84MB .. +256B)  parts f32  [64]              (live: K4 -> K5)
    const size_t NEEDED = 67108864ull + 20971520ull + 256ull;   // 88,080,640
    if (ws_size < NEEDED) {                 // deterministic across calls
        wsfail<<<1, 64, 0, stream>>>(out);
        return;
    }
    u16*   psiT  = (u16*)(ws);
    float* bp    = (float*)(ws);
    u16*   Sp    = (u16*)(ws + 67108864);
    float* parts = (float*)(ws + 88080384);

    psinorm_t<<<dim3(16, 64), 256, 0, stream>>>(psi, psiT);
    syrk_bf16<<<640,          256, 0, stream>>>(psiT, Sp);
    bgemm    <<<640,          256, 0, stream>>>(Sp, bp);
    bfinal   <<<64,           256, 0, stream>>>(bp, phi, parts);
    fsum     <<<1,            64,  0, stream>>>(parts, out);
}

// Round 8
// 268.751 us; speedup vs baseline: 1.1591x; 1.1591x over previous
//
#include <hip/hip_runtime.h>
#include <hip/hip_bf16.h>

typedef unsigned short u16;
typedef unsigned int u32;
typedef __attribute__((ext_vector_type(8))) short short8x;   // 8 bf16 (4 VGPR)
typedef __attribute__((ext_vector_type(4))) float f32x4;

__device__ __forceinline__ u16 bf16u(float x) {
    __hip_bfloat16 h = __float2bfloat16(x);
    return *reinterpret_cast<u16*>(&h);
}

__device__ __forceinline__ void gload_lds16(const void* g, void* l) {
    __builtin_amdgcn_global_load_lds(
        (const __attribute__((address_space(1))) u32*)g,
        (__attribute__((address_space(3))) u32*)l, 16, 0, 0);
}

// m=64, n=1024, W=H=512
#define M_  64
#define N_  1024
#define W_  512
#define SP_ROW 163840   // packed S' row length per i: 10 tiles * 16384

// ---------------------------------------------------------------------------
// K1 (grid 1040, block 256):
//  blocks 0..1023 : normalize psi rows (axis=2), write transposed bf16
//                   psiT[i][w][n]  (i = bid>>4, nb = bid&15)
//  blocks 1024+gb : gb=0..15 -> f32 phi-gram rows 4gb..4gb+3 -> g2[i][j];
//                   gb==0 additionally seeds out[0] = -m*n (stream-ordered
//                   before K3's atomics).
// ---------------------------------------------------------------------------
__global__ __launch_bounds__(256) void psinorm_t(const float* __restrict__ psi,
                                                 const float* __restrict__ phi,
                                                 u16* __restrict__ psiT,
                                                 float* __restrict__ g2,
                                                 float* __restrict__ out) {
    const int t = threadIdx.x;
    __shared__ u32 tile[64][257];       // u16[64][514]; transpose scratch (65.8 KB)
    __shared__ float djs[4][64], nsqs[64];

    if (blockIdx.x < 1024) {
        const int i  = blockIdx.x >> 4;
        const int nb = blockIdx.x & 15;
        const float* base = psi + ((size_t)i * N_ + (size_t)nb * 64) * W_;
        const int sub = t & 15;             // 16 threads per row

#pragma unroll
        for (int pp = 0; pp < 4; ++pp) {
            const int r = pp * 16 + (t >> 4);
            const float4* rb = (const float4*)(base + (size_t)r * W_) + sub;
            float4 v[8];
            float s = 0.f;
#pragma unroll
            for (int k = 0; k < 8; ++k) {
                v[k] = rb[k * 16];          // bytes: r*2048 + sub*16 + k*256
                s += v[k].x * v[k].x + v[k].y * v[k].y + v[k].z * v[k].z + v[k].w * v[k].w;
            }
#pragma unroll
            for (int o = 1; o < 16; o <<= 1) s += __shfl_xor(s, o);
            const float inv = 1.0f / fmaxf(sqrtf(s), 1e-12f);
#pragma unroll
            for (int k = 0; k < 8; ++k) {
                u32 p0 = (u32)bf16u(v[k].x * inv) | ((u32)bf16u(v[k].y * inv) << 16);
                u32 p1 = (u32)bf16u(v[k].z * inv) | ((u32)bf16u(v[k].w * inv) << 16);
                const int wh = sub * 2 + k * 32;    // u32 col; w = sub*4 + k*64
                tile[r][wh]     = p0;               // 2-way bank alias: free
                tile[r][wh + 1] = p1;
            }
        }
        __syncthreads();

        // transposed write: psiT[i][w][nb*64 + nn], u32 packs (nn = 2q, 2q+1)
        const u16* t16 = (const u16*)&tile[0][0];
        const int lane = t & 63, wv = t >> 6;
        const int q  = lane & 31;
        const int l5 = lane >> 5;
        u32* out32 = (u32*)psiT + (size_t)i * (W_ * N_ / 2) + nb * 32;
#pragma unroll 4
        for (int it = 0; it < 64; ++it) {
            const int w = it * 8 + wv * 2 + l5;
            u32 lo = (u32)t16[(2 * q)     * 514 + w];
            u32 hi = (u32)t16[(2 * q + 1) * 514 + w];
            out32[(size_t)w * 512 + q] = lo | (hi << 16);
        }
    } else {
        // ---- phi-gram path: rows i0..i0+3 of g2 ----
        const int gb = blockIdx.x - 1024;   // 0..15
        const int i0 = gb * 4;
        const int lane = t & 63, wv = t >> 6;
        float* pis = (float*)&tile[0][0];   // 4x512 f32 (8 KB of tile scratch)
#pragma unroll
        for (int r = 0; r < 4; ++r) {
            pis[r * 512 + t]       = phi[(i0 + r) * 512 + t];
            pis[r * 512 + 256 + t] = phi[(i0 + r) * 512 + 256 + t];
        }
        __syncthreads();

        for (int jj = 0; jj < 16; ++jj) {
            int j = wv + jj * 4;
            const float* pj = phi + j * 512;
            float nn = 0.f, d0 = 0.f, d1 = 0.f, d2 = 0.f, d3 = 0.f;
#pragma unroll
            for (int e = 0; e < 8; ++e) {
                float x = pj[lane + e * 64];
                nn += x * x;
                d0 += pis[0 * 512 + lane + e * 64] * x;
                d1 += pis[1 * 512 + lane + e * 64] * x;
                d2 += pis[2 * 512 + lane + e * 64] * x;
                d3 += pis[3 * 512 + lane + e * 64] * x;
            }
#pragma unroll
            for (int o = 32; o; o >>= 1) {
                nn += __shfl_xor(nn, o);
                d0 += __shfl_xor(d0, o);
                d1 += __shfl_xor(d1, o);
                d2 += __shfl_xor(d2, o);
                d3 += __shfl_xor(d3, o);
            }
            if (lane == 0) {
                djs[0][j] = d0; djs[1][j] = d1; djs[2][j] = d2; djs[3][j] = d3;
                nsqs[j] = nn;
            }
        }
        __syncthreads();
        if (t < 64) {
            const int j = t;
            const float invj = 1.0f / fmaxf(sqrtf(nsqs[j]), 1e-12f);
#pragma unroll
            for (int r = 0; r < 4; ++r) {
                const float invi = 1.0f / fmaxf(sqrtf(nsqs[i0 + r]), 1e-12f);
                const float g = djs[r][j] * invi * invj;
                g2[(i0 + r) * 64 + j] = g * g;
            }
        }
        if (gb == 0 && t == 0) out[0] = -65536.0f;   // -m*n seed for K3 atomics
    }
}

// ---------------------------------------------------------------------------
// K2: batched SYRK  S_i = psiT_i * psiT_i^T, upper-triangle 128x128 tiles only.
// psiT_i is 512(w) x 1024(n) bf16, k(=n)-contiguous: serves BOTH operands.
// grid 640 flat, XCD-swizzled: x=L&7, q=L>>3, i=x*8+q/10, bt=q%10 (bijective).
// block = 256 (4 waves, 2x2), BK = 64, 16 K-iters. T3-min double-buffer.
// XOR-swizzled LDS (source-side pre-swizzle, m173; involution on read).
// Output packed: Sp[i][tile] scaled by sqrt(2) on off-diag tiles so that
// b[i][j] = <Sp_i, Sp_j> reproduces the full Frobenius product exactly.
// ---------------------------------------------------------------------------
__global__ __launch_bounds__(256) void syrk_bf16(const u16* __restrict__ psiT,
                                                 u16* __restrict__ Sp) {
    const int L = blockIdx.x;
    const int q = L >> 3;
    const int i  = (L & 7) * 8 + q / 10;
    const int bt = q % 10;
    int tr, tc;
    if      (bt < 4) { tr = 0; tc = bt;     }
    else if (bt < 7) { tr = 1; tc = bt - 3; }
    else if (bt < 9) { tr = 2; tc = bt - 5; }
    else             { tr = 3; tc = 3;      }
    const int t = threadIdx.x;

    const u16* Abase = psiT + (size_t)i * W_ * N_ + (size_t)tr * 128 * N_;
    const u16* Bbase = psiT + (size_t)i * W_ * N_ + (size_t)tc * 128 * N_;

    __shared__ alignas(16) u16 ldsA[2][128][64];   // 2 x 16 KB
    __shared__ alignas(16) u16 ldsB[2][128][64];

    const int lane = t & 63, wv = t >> 6;
    const int wr = wv >> 1, wc = wv & 1;
    const int lrow = lane & 15, lk8 = lane >> 4;   // frag row / k-chunk

    auto STAGE = [&](int buf, int kt) {
        const int k0 = kt * 64;
#pragma unroll
        for (int r = 0; r < 4; ++r) {
            int c = r * 256 + t;
            int row = c >> 3, cch = c & 7;
            int scch = cch ^ (row & 7);            // pre-swizzled source chunk
            gload_lds16(Abase + (size_t)row * N_ + k0 + scch * 8, &ldsA[buf][row][cch * 8]);
            gload_lds16(Bbase + (size_t)row * N_ + k0 + scch * 8, &ldsB[buf][row][cch * 8]);
        }
    };

    f32x4 acc[4][4];
#pragma unroll
    for (int a = 0; a < 4; ++a)
#pragma unroll
        for (int b = 0; b < 4; ++b) acc[a][b] = (f32x4){0.f, 0.f, 0.f, 0.f};

    STAGE(0, 0);
    asm volatile("s_waitcnt vmcnt(0)" ::: "memory");
    __builtin_amdgcn_s_barrier();

    int cur = 0;
    for (int kt = 0; kt < 16; ++kt) {
        if (kt < 15) STAGE(cur ^ 1, kt + 1);       // issue next-tile loads early
#pragma unroll
        for (int ks = 0; ks < 2; ++ks) {
            short8x af[4], bf[4];
#pragma unroll
            for (int mf = 0; mf < 4; ++mf) {
                int row = wr * 64 + mf * 16 + lrow;
                int ch = (ks * 4 + lk8) ^ (row & 7);
                af[mf] = *(const short8x*)&ldsA[cur][row][ch * 8];
            }
#pragma unroll
            for (int nf = 0; nf < 4; ++nf) {
                int row = wc * 64 + nf * 16 + lrow;
                int ch = (ks * 4 + lk8) ^ (row & 7);
                bf[nf] = *(const short8x*)&ldsB[cur][row][ch * 8];
            }
#pragma unroll
            for (int mf = 0; mf < 4; ++mf)
#pragma unroll
                for (int nf = 0; nf < 4; ++nf)
                    acc[mf][nf] = __builtin_amdgcn_mfma_f32_16x16x32_bf16(
                        af[mf], bf[nf], acc[mf][nf], 0, 0, 0);
        }
        asm volatile("s_waitcnt vmcnt(0)" ::: "memory");
        __builtin_amdgcn_sched_barrier(0);
        __builtin_amdgcn_s_barrier();
        cur ^= 1;
    }

    // epilogue: C/D layout col=lane&15, row=(lane>>4)*4+reg (m89-verified).
    const float sc = (tr == tc) ? 1.0f : 1.41421356237f;
    size_t Sbase = (size_t)i * SP_ROW + (size_t)bt * 16384;
#pragma unroll
    for (int mf = 0; mf < 4; ++mf)
#pragma unroll
        for (int nf = 0; nf < 4; ++nf)
#pragma unroll
            for (int reg = 0; reg < 4; ++reg) {
                int wl = wr * 64 + mf * 16 + lk8 * 4 + reg;
                int vl = wc * 64 + nf * 16 + lrow;
                Sp[Sbase + (size_t)wl * 128 + vl] = bf16u(acc[mf][nf][reg] * sc);
            }
}

// ---------------------------------------------------------------------------
// K3: weighted split-K: partial = Sp * Sp^T over a 256-elem K-chunk, then
// contract with g2 in-register and atomicAdd ONE scalar into out.
// grid 640, block 256 (4 waves 2x2, each 32x32 of the 64x64 output).
// ---------------------------------------------------------------------------
__global__ __launch_bounds__(256) void bgemm_w(const u16* __restrict__ Sp,
                                               const float* __restrict__ g2,
                                               float* __restrict__ out) {
    const int t = threadIdx.x;
    const int lane = t & 63, wv = t >> 6;
    const int wr = wv >> 1, wc = wv & 1;
    const int lrow = lane & 15, lk8 = lane >> 4;
    const size_t kc0 = (size_t)blockIdx.x * 256;

    f32x4 acc[2][2];
#pragma unroll
    for (int a = 0; a < 2; ++a)
#pragma unroll
        for (int b = 0; b < 2; ++b) acc[a][b] = (f32x4){0.f, 0.f, 0.f, 0.f};

#pragma unroll
    for (int ks = 0; ks < 8; ++ks) {
        short8x af[2], bf[2];
#pragma unroll
        for (int mf = 0; mf < 2; ++mf) {
            int row = wr * 32 + mf * 16 + lrow;
            af[mf] = *(const short8x*)(Sp + (size_t)row * SP_ROW + kc0 + (ks * 4 + lk8) * 8);
        }
#pragma unroll
        for (int nf = 0; nf < 2; ++nf) {
            int row = wc * 32 + nf * 16 + lrow;
            bf[nf] = *(const short8x*)(Sp + (size_t)row * SP_ROW + kc0 + (ks * 4 + lk8) * 8);
        }
#pragma unroll
        for (int mf = 0; mf < 2; ++mf)
#pragma unroll
            for (int nf = 0; nf < 2; ++nf)
                acc[mf][nf] = __builtin_amdgcn_mfma_f32_16x16x32_bf16(
                    af[mf], bf[nf], acc[mf][nf], 0, 0, 0);
    }

    // weight by g2 (C/D layout: row = wr*32+mf*16+lk8*4+reg, col = wc*32+nf*16+lrow)
    float wsum = 0.f;
#pragma unroll
    for (int mf = 0; mf < 2; ++mf)
#pragma unroll
        for (int nf = 0; nf < 2; ++nf) {
            const int jc = wc * 32 + nf * 16 + lrow;
#pragma unroll
            for (int reg = 0; reg < 4; ++reg) {
                const int ir = wr * 32 + mf * 16 + lk8 * 4 + reg;
                wsum += acc[mf][nf][reg] * g2[ir * 64 + jc];
            }
        }
#pragma unroll
    for (int o = 32; o; o >>= 1) wsum += __shfl_down(wsum, o);
    __shared__ float w4[4];
    if (lane == 0) w4[wv] = wsum;
    __syncthreads();
    if (t == 0) atomicAdd(out, w4[0] + w4[1] + w4[2] + w4[3]);
}

// Fallback marker if workspace is too small (visible-wrong, not OOB-crash).
__global__ void wsfail(float* __restrict__ out) {
    if (threadIdx.x == 0) out[0] = 1.0e30f;
}

extern "C" void kernel_launch(void* const* d_in, const int* in_sizes, int n_in,
                              void* d_out, int out_size, void* d_ws, size_t ws_size,
                              hipStream_t stream) {
    const float* phi = (const float*)d_in[0];
    const float* psi = (const float*)d_in[1];
    float* out = (float*)d_out;
    char* ws = (char*)d_ws;

    // workspace layout (bytes):
    //   [0 .. 64MB)        psiT bf16 [64][512][1024]  (live: K1 -> K2)
    //   [64MB .. 84MB)     Sp   bf16 [64][163840]     (live: K2 -> K3)
    //   [84MB .. +16KB)    g2   f32  [64][64]         (live: K1 -> K3)
    const size_t NEEDED = 67108864ull + 20971520ull + 16384ull;   // 88,096,768
    if (ws_size < NEEDED) {
        wsfail<<<1, 64, 0, stream>>>(out);
        return;
    }
    u16*   psiT = (u16*)(ws);
    u16*   Sp   = (u16*)(ws + 67108864);
    float* g2   = (float*)(ws + 88080384);

    psinorm_t<<<1040, 256, 0, stream>>>(psi, phi, psiT, g2, out);
    syrk_bf16<<<640,  256, 0, stream>>>(psiT, Sp);
    bgemm_w  <<<640,  256, 0, stream>>>(Sp, g2, out);
}